// Round 1
// baseline (95.949 us; speedup 1.0000x reference)
//
#include <hip/hip_runtime.h>
#include <math.h>

#define N_ 32
#define C_ 64
#define T_ 128
#define V_ 25
#define K_ 10
// V*K = 250 floats = 125 float2 per (n,c,t) row; T*V = 3200 tv per (n,c)

// Kernel 1: mf[n,c,v,k] = (1/T) * sum_t rf[n,c,t,v,k]
// One block per (n,c); thread j owns float2 column j (125 active of 128).
__global__ __launch_bounds__(128) void mean_kernel(const float* __restrict__ rf,
                                                   float* __restrict__ mf) {
    const int nc = blockIdx.x;              // 0..N*C-1
    const int j  = threadIdx.x;             // float2 column
    if (j >= 125) return;
    const float2* rf2 = reinterpret_cast<const float2*>(rf);
    const size_t base = (size_t)nc * T_ * 125;
    float2 a0 = make_float2(0.f, 0.f), a1 = a0, a2 = a0, a3 = a0;
    for (int t = 0; t < T_; t += 4) {
        float2 x0 = rf2[base + (size_t)(t + 0) * 125 + j];
        float2 x1 = rf2[base + (size_t)(t + 1) * 125 + j];
        float2 x2 = rf2[base + (size_t)(t + 2) * 125 + j];
        float2 x3 = rf2[base + (size_t)(t + 3) * 125 + j];
        a0.x += x0.x; a0.y += x0.y;
        a1.x += x1.x; a1.y += x1.y;
        a2.x += x2.x; a2.y += x2.y;
        a3.x += x3.x; a3.y += x3.y;
    }
    float2 s;
    s.x = (a0.x + a1.x + a2.x + a3.x) * (1.0f / T_);
    s.y = (a0.y + a1.y + a2.y + a3.y) * (1.0f / T_);
    reinterpret_cast<float2*>(mf)[(size_t)nc * 125 + j] = s;
}

// Kernel 2: a[n,v,k] = sum_p softmax_p( sum_c mf[n,c,v,k]*w1[k,p,c] + b1[k,p] ) * w2[p]
// One block per n; thread = (v,k) pair (250 active of 256). w1 staged in LDS with
// padded stride 65 to break the k*640 bank aliasing.
__global__ __launch_bounds__(256) void attn_kernel(const float* __restrict__ mf,
                                                   const float* __restrict__ w1,
                                                   const float* __restrict__ b1,
                                                   const float* __restrict__ w2,
                                                   float* __restrict__ a_out) {
    __shared__ float w1s[K_ * K_ * 65];   // [kp][c] stride 65
    __shared__ float b1s[K_ * K_];
    __shared__ float w2s[K_];
    const int n   = blockIdx.x;
    const int tid = threadIdx.x;
    for (int i = tid; i < K_ * K_ * C_; i += 256) {
        int kp = i >> 6;          // /64
        int c  = i & 63;
        w1s[kp * 65 + c] = w1[i];
    }
    if (tid < K_ * K_) b1s[tid] = b1[tid];
    if (tid < K_)      w2s[tid] = w2[tid];
    __syncthreads();
    if (tid >= V_ * K_) return;
    const int k = tid % K_;
    // load this (v,k)'s mean-feature vector over c (stride 250)
    float mfv[C_];
    const float* mfp = mf + (size_t)n * C_ * (V_ * K_) + tid;
    #pragma unroll
    for (int c = 0; c < C_; ++c) mfv[c] = mfp[(size_t)c * (V_ * K_)];
    float lg[K_];
    #pragma unroll
    for (int p = 0; p < K_; ++p) {
        float s = b1s[k * K_ + p];
        const float* wrow = &w1s[(k * K_ + p) * 65];
        #pragma unroll
        for (int c = 0; c < C_; ++c) s += mfv[c] * wrow[c];
        lg[p] = s;
    }
    float m = lg[0];
    #pragma unroll
    for (int p = 1; p < K_; ++p) m = fmaxf(m, lg[p]);
    float se = 0.f, av = 0.f;
    #pragma unroll
    for (int p = 0; p < K_; ++p) {
        float e = __expf(lg[p] - m);
        se += e;
        av += e * w2s[p];
    }
    a_out[(size_t)n * (V_ * K_) + tid] = av / se;
}

// Kernel 3: out[n,c,t,v] = sum_k rf[n,c,t,v,k] * a[n,v,k] + b2
// Each block: one (n,c, chunk-of-640-tv). Each thread: 2 consecutive tv
// (20 floats = 5 aligned float4). a[n] (250 floats) staged in LDS.
__global__ __launch_bounds__(320) void out_kernel(const float* __restrict__ rf,
                                                  const float* __restrict__ a,
                                                  const float* __restrict__ b2,
                                                  float* __restrict__ out) {
    __shared__ float as[V_ * K_];
    const int b     = blockIdx.x;
    const int chunk = b % 5;
    const int nc    = b / 5;
    const int n     = nc / C_;
    if (threadIdx.x < V_ * K_) as[threadIdx.x] = a[(size_t)n * (V_ * K_) + threadIdx.x];
    __syncthreads();
    const float bias = b2[0];
    const int tv0 = chunk * 640 + threadIdx.x * 2;      // even
    const size_t obase = (size_t)nc * (T_ * V_) + tv0;  // even
    const float4* p = reinterpret_cast<const float4*>(rf + obase * K_);
    float4 x0 = p[0], x1 = p[1], x2 = p[2], x3 = p[3], x4 = p[4];
    const int v0 = tv0 % V_;
    const int v1 = (tv0 + 1) % V_;
    const float* a0 = &as[v0 * K_];
    const float* a1 = &as[v1 * K_];
    float o0 = bias
             + x0.x * a0[0] + x0.y * a0[1] + x0.z * a0[2] + x0.w * a0[3]
             + x1.x * a0[4] + x1.y * a0[5] + x1.z * a0[6] + x1.w * a0[7]
             + x2.x * a0[8] + x2.y * a0[9];
    float o1 = bias
             + x2.z * a1[0] + x2.w * a1[1]
             + x3.x * a1[2] + x3.y * a1[3] + x3.z * a1[4] + x3.w * a1[5]
             + x4.x * a1[6] + x4.y * a1[7] + x4.z * a1[8] + x4.w * a1[9];
    float2 o;
    o.x = o0;
    o.y = o1;
    reinterpret_cast<float2*>(out)[obase >> 1] = o;
}

extern "C" void kernel_launch(void* const* d_in, const int* in_sizes, int n_in,
                              void* d_out, int out_size, void* d_ws, size_t ws_size,
                              hipStream_t stream) {
    const float* rf = (const float*)d_in[0];   // (N,C,T,V,K) fp32
    const float* w1 = (const float*)d_in[1];   // (K,K,C)
    const float* b1 = (const float*)d_in[2];   // (K,K)
    const float* w2 = (const float*)d_in[3];   // (K,)
    const float* b2 = (const float*)d_in[4];   // (1,)
    float* out = (float*)d_out;                // (N,C,T,V)

    float* mf    = (float*)d_ws;                           // N*C*V*K = 512000 floats
    float* a_vk  = (float*)((char*)d_ws + (size_t)N_ * C_ * V_ * K_ * sizeof(float)); // 8000 floats

    mean_kernel<<<N_ * C_, 128, 0, stream>>>(rf, mf);
    attn_kernel<<<N_, 256, 0, stream>>>(mf, w1, b1, w2, a_vk);
    out_kernel<<<N_ * C_ * 5, 320, 0, stream>>>(rf, a_vk, b2, out);
}

// Round 2
// 92.766 us; speedup vs baseline: 1.0343x; 1.0343x over previous
//
#include <hip/hip_runtime.h>
#include <math.h>

#define N_ 32
#define C_ 64
#define T_ 128
#define V_ 25
#define K_ 10
// V*K = 250 floats per (n,c,t) row; slab per (n,c) = T*250 = 32000 floats = 8000 float4
// 1000 floats (= 4 rows) == 250 float4, and 1000 % 250 == 0, so a float4 at flat
// offset 4j + 1000*i always covers columns (4j..4j+3) mod 250 regardless of i.

// Kernel 1: mf[n,c,v,k] = (1/T) * sum_t rf[n,c,t,v,k]
// Flat float4 streaming (16 B/lane, 1 KiB/wave contiguous), column sums folded
// via LDS f32 atomics (2-way contention max).
__global__ __launch_bounds__(256) void mean_kernel(const float* __restrict__ rf,
                                                   float* __restrict__ mf) {
    __shared__ float as[V_ * K_];
    const int nc = blockIdx.x;          // 0..N*C-1
    const int j  = threadIdx.x;         // float4 lane within the 1000-float group
    if (j < V_ * K_) as[j] = 0.f;
    __syncthreads();
    if (j < 250) {
        const float4* rf4 = reinterpret_cast<const float4*>(rf) + (size_t)nc * 8000 + j;
        float4 s = make_float4(0.f, 0.f, 0.f, 0.f);
        #pragma unroll 8
        for (int i = 0; i < 32; ++i) {      // 32 groups of 4 rows
            float4 x = rf4[(size_t)i * 250];
            s.x += x.x; s.y += x.y; s.z += x.z; s.w += x.w;
        }
        const int c0 = (4 * j) % 250;       // even, <= 248
        atomicAdd(&as[c0], s.x);
        atomicAdd(&as[(c0 + 1) % 250], s.y);
        atomicAdd(&as[(c0 + 2) % 250], s.z);
        atomicAdd(&as[(c0 + 3) % 250], s.w);
    }
    __syncthreads();
    if (j < 125) {
        float2 o;
        o.x = as[2 * j]     * (1.0f / T_);
        o.y = as[2 * j + 1] * (1.0f / T_);
        reinterpret_cast<float2*>(mf)[(size_t)nc * 125 + j] = o;
    }
}

// Kernel 2: a[n,v,k] = sum_p softmax_p( sum_c mf[n,c,v,k]*w1[k,p,c] + b1[k,p] ) * w2[p]
// One block per n; thread = (v,k) pair (250 active of 256). mf loads are
// lane-coalesced (consecutive vk). w1 staged in LDS, stride 65 to break bank aliasing.
__global__ __launch_bounds__(256) void attn_kernel(const float* __restrict__ mf,
                                                   const float* __restrict__ w1,
                                                   const float* __restrict__ b1,
                                                   const float* __restrict__ w2,
                                                   float* __restrict__ a_out) {
    __shared__ float w1s[K_ * K_ * 65];   // [kp][c] stride 65
    __shared__ float b1s[K_ * K_];
    __shared__ float w2s[K_];
    const int n   = blockIdx.x;
    const int tid = threadIdx.x;
    for (int i = tid; i < K_ * K_ * C_; i += 256) {
        int kp = i >> 6;          // /64
        int c  = i & 63;
        w1s[kp * 65 + c] = w1[i];
    }
    if (tid < K_ * K_) b1s[tid] = b1[tid];
    if (tid < K_)      w2s[tid] = w2[tid];
    __syncthreads();
    if (tid >= V_ * K_) return;
    const int k = tid % K_;
    float mfv[C_];
    const float* mfp = mf + (size_t)n * C_ * (V_ * K_) + tid;
    #pragma unroll
    for (int c = 0; c < C_; ++c) mfv[c] = mfp[(size_t)c * (V_ * K_)];
    float lg[K_];
    #pragma unroll
    for (int p = 0; p < K_; ++p) {
        float s = b1s[k * K_ + p];
        const float* wrow = &w1s[(k * K_ + p) * 65];
        #pragma unroll
        for (int c = 0; c < C_; ++c) s += mfv[c] * wrow[c];
        lg[p] = s;
    }
    float m = lg[0];
    #pragma unroll
    for (int p = 1; p < K_; ++p) m = fmaxf(m, lg[p]);
    float se = 0.f, av = 0.f;
    #pragma unroll
    for (int p = 0; p < K_; ++p) {
        float e = __expf(lg[p] - m);
        se += e;
        av += e * w2s[p];
    }
    a_out[(size_t)n * (V_ * K_) + tid] = av / se;
}

// Kernel 3: out[n,c,t,v] = sum_k rf[n,c,t,v,k] * a[n,v,k] + b2
// Each block: one (n,c, chunk-of-640-tv). Each thread: 2 consecutive tv
// (20 floats = 5 aligned float4). a[n] (250 floats) staged in LDS.
__global__ __launch_bounds__(320) void out_kernel(const float* __restrict__ rf,
                                                  const float* __restrict__ a,
                                                  const float* __restrict__ b2,
                                                  float* __restrict__ out) {
    __shared__ float as[V_ * K_];
    const int b     = blockIdx.x;
    const int chunk = b % 5;
    const int nc    = b / 5;
    const int n     = nc / C_;
    if (threadIdx.x < V_ * K_) as[threadIdx.x] = a[(size_t)n * (V_ * K_) + threadIdx.x];
    __syncthreads();
    const float bias = b2[0];
    const int tv0 = chunk * 640 + threadIdx.x * 2;      // even
    const size_t obase = (size_t)nc * (T_ * V_) + tv0;  // even
    const float4* p = reinterpret_cast<const float4*>(rf + obase * K_);
    float4 x0 = p[0], x1 = p[1], x2 = p[2], x3 = p[3], x4 = p[4];
    const int v0 = tv0 % V_;
    const int v1 = (tv0 + 1) % V_;
    const float* a0 = &as[v0 * K_];
    const float* a1 = &as[v1 * K_];
    float o0 = bias
             + x0.x * a0[0] + x0.y * a0[1] + x0.z * a0[2] + x0.w * a0[3]
             + x1.x * a0[4] + x1.y * a0[5] + x1.z * a0[6] + x1.w * a0[7]
             + x2.x * a0[8] + x2.y * a0[9];
    float o1 = bias
             + x2.z * a1[0] + x2.w * a1[1]
             + x3.x * a1[2] + x3.y * a1[3] + x3.z * a1[4] + x3.w * a1[5]
             + x4.x * a1[6] + x4.y * a1[7] + x4.z * a1[8] + x4.w * a1[9];
    float2 o;
    o.x = o0;
    o.y = o1;
    reinterpret_cast<float2*>(out)[obase >> 1] = o;
}

extern "C" void kernel_launch(void* const* d_in, const int* in_sizes, int n_in,
                              void* d_out, int out_size, void* d_ws, size_t ws_size,
                              hipStream_t stream) {
    const float* rf = (const float*)d_in[0];   // (N,C,T,V,K) fp32
    const float* w1 = (const float*)d_in[1];   // (K,K,C)
    const float* b1 = (const float*)d_in[2];   // (K,K)
    const float* w2 = (const float*)d_in[3];   // (K,)
    const float* b2 = (const float*)d_in[4];   // (1,)
    float* out = (float*)d_out;                // (N,C,T,V)

    float* mf   = (float*)d_ws;                // N*C*V*K = 512000 floats
    float* a_vk = (float*)((char*)d_ws + (size_t)N_ * C_ * V_ * K_ * sizeof(float)); // 8000 floats

    mean_kernel<<<N_ * C_, 256, 0, stream>>>(rf, mf);
    attn_kernel<<<N_, 256, 0, stream>>>(mf, w1, b1, w2, a_vk);
    out_kernel<<<N_ * C_ * 5, 320, 0, stream>>>(rf, a_vk, b2, out);
}